// Round 3
// baseline (1440.549 us; speedup 1.0000x reference)
//
#include <hip/hip_runtime.h>
#include <math.h>

// Problem constants
constexpr int Bb = 4, Ll = 2048, Ss = 2048, Hh = 16, Ee = 64;
constexpr float S2E  = 0.125f * 1.44269504088896341f;  // SCALE * log2(e)
constexpr float EPS2 = 1e-8f * S2E * S2E;
constexpr float INV_CNT = 1.0f / (4.0f * 16.0f * 2048.0f * 2048.0f);
// scsum accumulates score*log2(e); convert back with ln2
constexpr float SUM_SCALE = INV_CNT * 0.69314718055994531f;

typedef __attribute__((ext_vector_type(8)))  short short8;   // 8 x bf16 bits
typedef __attribute__((ext_vector_type(4)))  float floatx4;
typedef __attribute__((ext_vector_type(16))) float floatx16; // 32x32 MFMA C/D

#define MFMA32 __builtin_amdgcn_mfma_f32_32x32x16_bf16

// async global(16B/lane) -> LDS (wave-uniform dst base + lane*16)
#define GLL(gp, lp_)                                                       \
  __builtin_amdgcn_global_load_lds(                                        \
      (const __attribute__((address_space(1))) unsigned int*)(gp),         \
      (__attribute__((address_space(3))) unsigned int*)(lp_), 16, 0, 0)

__device__ __forceinline__ unsigned bfrnd(float f) {  // RNE, bf16 in high 16
  unsigned u = __builtin_bit_cast(unsigned, f);
  return u + 0x7fffu + ((u >> 16) & 1u);
}
__device__ __forceinline__ float sq4(float4 v) {
  return v.x * v.x + v.y * v.y + v.z * v.z + v.w * v.w;
}
__device__ __forceinline__ float4 mul4(float4 v, float s) {
  float4 r; r.x = v.x * s; r.y = v.y * s; r.z = v.z * s; r.w = v.w * s;
  return r;
}
__device__ __forceinline__ short8 pack8(float4 x, float4 y) {
  union { short8 s; unsigned u[4]; } r;
  r.u[0] = __builtin_amdgcn_perm(bfrnd(x.y), bfrnd(x.x), 0x07060302u);
  r.u[1] = __builtin_amdgcn_perm(bfrnd(x.w), bfrnd(x.z), 0x07060302u);
  r.u[2] = __builtin_amdgcn_perm(bfrnd(y.y), bfrnd(y.x), 0x07060302u);
  r.u[3] = __builtin_amdgcn_perm(bfrnd(y.w), bfrnd(y.z), 0x07060302u);
  return r.s;
}
// v_permlane32_swap_b32: a.hi32 <-> b.lo32.
__device__ __forceinline__ void pl32swap(unsigned &a, unsigned &b) {
  asm("v_permlane32_swap_b32 %0, %1" : "+v"(a), "+v"(b));
}

// ---------- Pre-pass: K->bf16 [bh][s][e], V->bf16^T [bh][e][s] (LDS-transposed,
// coalesced 128B output segments), kn2 ----------
__global__ __launch_bounds__(256) void geom_pre_kernel(
    const float* __restrict__ Kg, const float* __restrict__ Vg,
    short* __restrict__ Kbf, short* __restrict__ Vtg,
    float* __restrict__ kn2g, float* __restrict__ sumg) {
  __shared__ __align__(16) short vsm[64 * 66];  // [e-row][66 shorts] 132B stride
  const int tid = threadIdx.x, bid = blockIdx.x;
  const int st = bid & 31, h = (bid >> 5) & 15, b = bid >> 9;
  const int s0 = st * 64, bh = b * 16 + h;
  if (bid == 0 && tid == 0) *sumg = 0.0f;

  // K + kn2 (coalesced float4 reads, b128 bf16 writes)
  const int r64 = tid >> 2, ec = (tid & 3) * 16;
  const float4* kp = (const float4*)(Kg + (((size_t)b * Ss + s0 + r64) * Hh + h) * Ee + ec);
  float4 k0 = kp[0], k1 = kp[1], k2 = kp[2], k3 = kp[3];
  float kn = sq4(k0) + sq4(k1) + sq4(k2) + sq4(k3);
  kn += __shfl_xor(kn, 1);
  kn += __shfl_xor(kn, 2);
  if ((tid & 3) == 0) kn2g[(size_t)bh * Ss + s0 + r64] = kn;
  short* ko = Kbf + ((size_t)bh * Ss + s0 + r64) * Ee + ec;
  *(short8*)(ko)     = pack8(k0, k1);
  *(short8*)(ko + 8) = pack8(k2, k3);

  // V: read 4 s-rows x 4 e-cols, convert, transpose via LDS
  const int sq = tid >> 4, eq = tid & 15;
  const float* vb = Vg + (((size_t)b * Ss + s0 + sq * 4) * Hh + h) * Ee + eq * 4;
  float4 r0 = *(const float4*)(vb);
  float4 r1 = *(const float4*)(vb + Hh * Ee);
  float4 r2 = *(const float4*)(vb + 2 * Hh * Ee);
  float4 r3 = *(const float4*)(vb + 3 * Hh * Ee);
#pragma unroll
  for (int j = 0; j < 4; ++j) {
    unsigned lo = __builtin_amdgcn_perm(bfrnd((&r1.x)[j]), bfrnd((&r0.x)[j]), 0x07060302u);
    unsigned hh = __builtin_amdgcn_perm(bfrnd((&r3.x)[j]), bfrnd((&r2.x)[j]), 0x07060302u);
    short* row = vsm + (eq * 4 + j) * 66 + sq * 4;  // e-row, s = sq*4..+3
    *(unsigned*)(row)     = lo;
    *(unsigned*)(row + 2) = hh;
  }
  __syncthreads();
  // write out: thread -> e-row = tid>>2, 32B s-chunk = (tid&3)*16 shorts
  const int e = tid >> 2, sc = (tid & 3) * 16;
  const short* rr = vsm + e * 66 + sc;
  uint4 a, c;
  a.x = *(const unsigned*)(rr + 0);  a.y = *(const unsigned*)(rr + 2);
  a.z = *(const unsigned*)(rr + 4);  a.w = *(const unsigned*)(rr + 6);
  c.x = *(const unsigned*)(rr + 8);  c.y = *(const unsigned*)(rr + 10);
  c.z = *(const unsigned*)(rr + 12); c.w = *(const unsigned*)(rr + 14);
  short* vo = Vtg + ((size_t)bh * Ee + e) * Ss + s0 + sc;
  *(uint4*)(vo)     = a;
  *(uint4*)(vo + 8) = c;
}

// ---------- Main: flash attention, 32x32 MFMA, S^T orientation, split-S ----------
// 512 threads / 8 waves: waves 0-3 process S[0,1024), waves 4-7 S[1024,2048),
// same 128 l-rows; partial (o,lp) combine additively (no running max) via LDS.
// Occupancy: 4 blocks/CU x 8 waves = 32 waves/CU (100% of wave slots).
// LDS (bytes): K [g][buf] 4x4096 [0,16384)  V^T 4x4096 [16384,32768)
//              kn2 [32768,40960)  (combine reuses [0,32768) + lp at 32768)
constexpr int KB0 = 0, VB0 = 16384, KN2 = 32768;

__global__ __launch_bounds__(512, 8) void geom_attn_kernel(
    const float* __restrict__ Qg, const short* __restrict__ Kbf,
    const short* __restrict__ Vtg, const float* __restrict__ kn2g,
    float* __restrict__ outg, float* __restrict__ sumg) {
  __shared__ __align__(16) char smem[40960];

  const int tid = threadIdx.x, w = tid >> 6, lane = tid & 63;
  const int l31 = lane & 31, hi = lane >> 5;
  const int g = w >> 2, wl = w & 3;    // S-half group, wave-in-group
  const int vt = tid & 255;            // thread id within group
  const int bid = blockIdx.x;
  const int lt = bid & 15, h = (bid >> 4) & 15, b = bid >> 8;
  const int bh = b * 16 + h;
  const int l0w = lt * 128 + wl * 32;

  // Q B-frags (col = l31, k-slice = ks*16 + hi*8 + 0..7), pre-scaled by S2E
  short8 qB[4];
  float qn2v;
  {
    const float* qrow = Qg + (((size_t)b * Ll + l0w + l31) * Hh + h) * Ee;
    float qn = 0.f;
#pragma unroll
    for (int ks = 0; ks < 4; ++ks) {
      float4 a0 = mul4(*(const float4*)(qrow + ks * 16 + hi * 8), S2E);
      float4 a1 = mul4(*(const float4*)(qrow + ks * 16 + hi * 8 + 4), S2E);
      qn += sq4(a0) + sq4(a1);
      qB[ks] = pack8(a0, a1);
    }
    qn += __shfl_xor(qn, 32);  // other hi half holds the other 32 elems
    qn2v = qn;
  }

  // staging source pointers (XOR-swizzled 16B granules), offset by S-half
  const int rK = vt >> 3, pK = vt & 7;
  const char* kSrc = (const char*)Kbf + (size_t)bh * (Ss * 128) + (size_t)g * (1024 * 128)
                     + rK * 128 + ((pK ^ (rK & 7)) * 16);
  const int eV = vt >> 2;
  const char* vSrc = (const char*)Vtg + (size_t)bh * (Ss * 128) + eV * (Ss * 2)
                     + g * 2048 + (((vt & 3) ^ (eV & 3)) * 16);
  char* kDstW = smem + KB0 + g * 8192 + wl * 1024;  // + buf*4096
  char* vDstW = smem + VB0 + g * 8192 + wl * 1024;

  // kn2 -> LDS once (8 KB, full S; one 1KB GLL per wave)
  GLL((const char*)kn2g + (size_t)bh * 8192 + (size_t)tid * 16, smem + KN2 + w * 1024);

  // prologue: stage tile 0 into buffer 0
  GLL(kSrc, kDstW);
  GLL(vSrc, vDstW);
  kSrc += 4096;
  vSrc += 64;

  floatx16 o[2] = {};
  float lp = 0.f, scsum = 0.f;

  const int kSwz = l31 & 7;  // K tile: row s31=l31, granule (2ks+hi)^kSwz
  const int vSwz = l31 & 3;  // V tile: row et*32+e31, granule (2ks2+hi)^vSwz
  const char* KbB = smem + KB0 + g * 8192;
  const char* VbB = smem + VB0 + g * 8192;
  const int knB = KN2 + g * 4096;

  for (int it = 0; it < 32; ++it) {
    const int p = it & 1;
    __syncthreads();  // tile it resident in buf p; prior compute done everywhere
    // prefetch tile it+1 (drained at NEXT barrier -> full tile of latency hiding)
    GLL(kSrc, kDstW + (p ^ 1) * 4096);
    GLL(vSrc, vDstW + (p ^ 1) * 4096);
    kSrc += 4096;
    vSrc += 64;

    const char* Kb = KbB + p * 4096;
    const char* Vb = VbB + p * 4096;

    // ---- K.Q^T -> S^T tile (32s x 32l); lane: col l=l31, rows s=(r&3)+8*(r>>2)+4*hi
    short8 ka0 = *(const short8*)(Kb + l31 * 128 + (((0 + hi) ^ kSwz) * 16));
    short8 ka1 = *(const short8*)(Kb + l31 * 128 + (((2 + hi) ^ kSwz) * 16));
    short8 ka2 = *(const short8*)(Kb + l31 * 128 + (((4 + hi) ^ kSwz) * 16));
    short8 ka3 = *(const short8*)(Kb + l31 * 128 + (((6 + hi) ^ kSwz) * 16));
    floatx16 d = {};
    d = MFMA32(ka0, qB[0], d, 0, 0, 0);
    d = MFMA32(ka1, qB[1], d, 0, 0, 0);
    d = MFMA32(ka2, qB[2], d, 0, 0, 0);
    d = MFMA32(ka3, qB[3], d, 0, 0, 0);

    // V B-frags (issue early; needed only at PV)
    short8 vb00 = *(const short8*)(Vb + l31 * 64 + (((0 + hi) ^ vSwz) * 16));
    short8 vb01 = *(const short8*)(Vb + l31 * 64 + (((2 + hi) ^ vSwz) * 16));
    short8 vb10 = *(const short8*)(Vb + (32 + l31) * 64 + (((0 + hi) ^ vSwz) * 16));
    short8 vb11 = *(const short8*)(Vb + (32 + l31) * 64 + (((2 + hi) ^ vSwz) * 16));

    // kn2 broadcast reads: knv[q] covers s = g*1024 + it*32 + 8q + 4hi + 0..3
    float4 knv0 = *(const float4*)(smem + knB + it * 128 + 0 * 32 + hi * 16);
    float4 knv1 = *(const float4*)(smem + knB + it * 128 + 1 * 32 + hi * 16);
    float4 knv2 = *(const float4*)(smem + knB + it * 128 + 2 * 32 + hi * 16);
    float4 knv3 = *(const float4*)(smem + knB + it * 128 + 3 * 32 + hi * 16);

    // ---- wedge scores + exp; pack to bf16 dword pairs
    unsigned pk[4][2];
#pragma unroll
    for (int q = 0; q < 4; ++q) {
      const float4 knq = (q == 0) ? knv0 : (q == 1) ? knv1 : (q == 2) ? knv2 : knv3;
      float pe[4];
#pragma unroll
      for (int r = 0; r < 4; ++r) {
        float dot = d[4 * q + r];
        float w2 = fmaf(-dot, dot, qn2v * (&knq.x)[r]);
        w2 = fmaxf(w2, EPS2);
        float rt = __builtin_amdgcn_sqrtf(w2);   // = score*log2(e)
        scsum += rt;
        float e = __builtin_amdgcn_exp2f(rt);    // exp(score), no max-sub
        lp += e;
        pe[r] = e;
      }
      pk[q][0] = __builtin_amdgcn_perm(__builtin_bit_cast(unsigned, pe[1]),
                                       __builtin_bit_cast(unsigned, pe[0]), 0x07060302u);
      pk[q][1] = __builtin_amdgcn_perm(__builtin_bit_cast(unsigned, pe[3]),
                                       __builtin_bit_cast(unsigned, pe[2]), 0x07060302u);
    }

    // ---- in-register P redistribution (4 permlane32_swap) ----
    pl32swap(pk[0][0], pk[1][0]);
    pl32swap(pk[0][1], pk[1][1]);
    pl32swap(pk[2][0], pk[3][0]);
    pl32swap(pk[2][1], pk[3][1]);
    union { unsigned u[4]; short8 s; } pa0, pa1;
    pa0.u[0] = pk[0][0]; pa0.u[1] = pk[0][1]; pa0.u[2] = pk[1][0]; pa0.u[3] = pk[1][1];
    pa1.u[0] = pk[2][0]; pa1.u[1] = pk[2][1]; pa1.u[2] = pk[3][0]; pa1.u[3] = pk[3][1];

    // ---- P.V (O[32l x 64e], 2 e-tiles x 2 k-steps)
    o[0] = MFMA32(pa0.s, vb00, o[0], 0, 0, 0);
    o[0] = MFMA32(pa1.s, vb01, o[0], 0, 0, 0);
    o[1] = MFMA32(pa0.s, vb10, o[1], 0, 0, 0);
    o[1] = MFMA32(pa1.s, vb11, o[1], 0, 0, 0);
  }

  __syncthreads();  // drain trailing prefetch; all K/V/kn2 reads done

  // ---- cross-half combine through LDS (reuse K/V space) ----
  float* lds_f = (float*)smem;
  if (g == 1) {
    float* base0 = lds_f + wl * 2048;  // 8KB per wave
#pragma unroll
    for (int r = 0; r < 16; ++r) {
      base0[r * 64 + lane]        = o[0][r];
      base0[(16 + r) * 64 + lane] = o[1][r];
    }
    lds_f[8192 + wl * 64 + lane] = lp;  // at byte 32768 (kn2 region, now dead)
  }
  __syncthreads();
  if (g == 0) {
    const float* base0 = lds_f + wl * 2048;
#pragma unroll
    for (int r = 0; r < 16; ++r) {
      o[0][r] += base0[r * 64 + lane];
      o[1][r] += base0[(16 + r) * 64 + lane];
    }
    lp += lds_f[8192 + wl * 64 + lane];

    // softmax denominator: fold the 2 hi replicas; lanes 0..31 hold lp[l31]
    lp += __shfl_xor(lp, 32);
    float lpinv = 1.0f / lp;

    // epilogue: lane (e31=l31, hi) holds O[row][et*32+e31], row=(r&3)+8*(r>>2)+4*hi
#pragma unroll
    for (int r = 0; r < 16; ++r) {
      const int row = (r & 3) + 8 * (r >> 2) + 4 * hi;
      float inv = __shfl(lpinv, row);
      float* orow = outg + (((size_t)b * Ll + l0w + row) * Hh + h) * Ee + l31;
      orow[0]  = o[0][r] * inv;
      orow[32] = o[1][r] * inv;
    }
  }

  // mean|scores|: wave-reduce, one atomic per wave (all 8 waves hold partials)
  scsum += __shfl_xor(scsum, 1);
  scsum += __shfl_xor(scsum, 2);
  scsum += __shfl_xor(scsum, 4);
  scsum += __shfl_xor(scsum, 8);
  scsum += __shfl_xor(scsum, 16);
  scsum += __shfl_xor(scsum, 32);
  if (lane == 0) atomicAdd(sumg, scsum * SUM_SCALE);
}

extern "C" void kernel_launch(void* const* d_in, const int* in_sizes, int n_in,
                              void* d_out, int out_size, void* d_ws, size_t ws_size,
                              hipStream_t stream) {
  const float* Q = (const float*)d_in[0];
  const float* K = (const float*)d_in[1];
  const float* V = (const float*)d_in[2];
  float* out   = (float*)d_out;
  float* sumsc = out + (size_t)Bb * Ll * Hh * Ee;

  // workspace: Kbf 16.78 MB | Vt 16.78 MB | kn2 0.52 MB (ws >= 34.1 MB)
  short* Kbf = (short*)d_ws;
  short* Vtg = Kbf + (size_t)Bb * Hh * Ss * Ee;
  float* kn2 = (float*)(Vtg + (size_t)Bb * Hh * Ee * Ss);

  hipLaunchKernelGGL(geom_pre_kernel, dim3(Bb * Hh * (Ss / 64)), dim3(256), 0,
                     stream, K, V, Kbf, Vtg, kn2, sumsc);
  hipLaunchKernelGGL(geom_attn_kernel, dim3(Bb * Hh * (Ll / 128)), dim3(512), 0,
                     stream, Q, Kbf, Vtg, kn2, out, sumsc);
}

// Round 4
// 253.281 us; speedup vs baseline: 5.6876x; 5.6876x over previous
//
#include <hip/hip_runtime.h>
#include <math.h>

// Problem constants
constexpr int Bb = 4, Ll = 2048, Ss = 2048, Hh = 16, Ee = 64;
constexpr float S2E  = 0.125f * 1.44269504088896341f;  // SCALE * log2(e)
constexpr float EPS2 = 1e-8f * S2E * S2E;
constexpr float INV_CNT = 1.0f / (4.0f * 16.0f * 2048.0f * 2048.0f);
// scsum accumulates score*log2(e); convert back with ln2
constexpr float SUM_SCALE = INV_CNT * 0.69314718055994531f;

typedef __attribute__((ext_vector_type(8)))  short short8;   // 8 x bf16 bits
typedef __attribute__((ext_vector_type(4)))  float floatx4;
typedef __attribute__((ext_vector_type(16))) float floatx16; // 32x32 MFMA C/D

#define MFMA32 __builtin_amdgcn_mfma_f32_32x32x16_bf16

// async global(16B/lane) -> LDS (wave-uniform dst base + lane*16)
#define GLL(gp, lp_)                                                       \
  __builtin_amdgcn_global_load_lds(                                        \
      (const __attribute__((address_space(1))) unsigned int*)(gp),         \
      (__attribute__((address_space(3))) unsigned int*)(lp_), 16, 0, 0)

__device__ __forceinline__ unsigned bfrnd(float f) {  // RNE, bf16 in high 16
  unsigned u = __builtin_bit_cast(unsigned, f);
  return u + 0x7fffu + ((u >> 16) & 1u);
}
__device__ __forceinline__ float sq4(float4 v) {
  return v.x * v.x + v.y * v.y + v.z * v.z + v.w * v.w;
}
__device__ __forceinline__ float4 mul4(float4 v, float s) {
  float4 r; r.x = v.x * s; r.y = v.y * s; r.z = v.z * s; r.w = v.w * s;
  return r;
}
__device__ __forceinline__ short8 pack8(float4 x, float4 y) {
  union { short8 s; unsigned u[4]; } r;
  r.u[0] = __builtin_amdgcn_perm(bfrnd(x.y), bfrnd(x.x), 0x07060302u);
  r.u[1] = __builtin_amdgcn_perm(bfrnd(x.w), bfrnd(x.z), 0x07060302u);
  r.u[2] = __builtin_amdgcn_perm(bfrnd(y.y), bfrnd(y.x), 0x07060302u);
  r.u[3] = __builtin_amdgcn_perm(bfrnd(y.w), bfrnd(y.z), 0x07060302u);
  return r.s;
}
// v_permlane32_swap_b32: a.hi32 <-> b.lo32.
__device__ __forceinline__ void pl32swap(unsigned &a, unsigned &b) {
  asm("v_permlane32_swap_b32 %0, %1" : "+v"(a), "+v"(b));
}

// ---------- Pre-pass: K->bf16 [bh][s][e], V->bf16^T [bh][e][s] (LDS-transposed,
// coalesced 128B output segments), kn2 ----------
__global__ __launch_bounds__(256) void geom_pre_kernel(
    const float* __restrict__ Kg, const float* __restrict__ Vg,
    short* __restrict__ Kbf, short* __restrict__ Vtg,
    float* __restrict__ kn2g, float* __restrict__ sumg) {
  __shared__ __align__(16) short vsm[64 * 66];  // [e-row][66 shorts] 132B stride
  const int tid = threadIdx.x, bid = blockIdx.x;
  const int st = bid & 31, h = (bid >> 5) & 15, b = bid >> 9;
  const int s0 = st * 64, bh = b * 16 + h;
  if (bid == 0 && tid == 0) *sumg = 0.0f;

  // K + kn2 (coalesced float4 reads, b128 bf16 writes)
  const int r64 = tid >> 2, ec = (tid & 3) * 16;
  const float4* kp = (const float4*)(Kg + (((size_t)b * Ss + s0 + r64) * Hh + h) * Ee + ec);
  float4 k0 = kp[0], k1 = kp[1], k2 = kp[2], k3 = kp[3];
  float kn = sq4(k0) + sq4(k1) + sq4(k2) + sq4(k3);
  kn += __shfl_xor(kn, 1);
  kn += __shfl_xor(kn, 2);
  if ((tid & 3) == 0) kn2g[(size_t)bh * Ss + s0 + r64] = kn;
  short* ko = Kbf + ((size_t)bh * Ss + s0 + r64) * Ee + ec;
  *(short8*)(ko)     = pack8(k0, k1);
  *(short8*)(ko + 8) = pack8(k2, k3);

  // V: read 4 s-rows x 4 e-cols, convert, transpose via LDS
  const int sq = tid >> 4, eq = tid & 15;
  const float* vb = Vg + (((size_t)b * Ss + s0 + sq * 4) * Hh + h) * Ee + eq * 4;
  float4 r0 = *(const float4*)(vb);
  float4 r1 = *(const float4*)(vb + Hh * Ee);
  float4 r2 = *(const float4*)(vb + 2 * Hh * Ee);
  float4 r3 = *(const float4*)(vb + 3 * Hh * Ee);
#pragma unroll
  for (int j = 0; j < 4; ++j) {
    unsigned lo = __builtin_amdgcn_perm(bfrnd((&r1.x)[j]), bfrnd((&r0.x)[j]), 0x07060302u);
    unsigned hh = __builtin_amdgcn_perm(bfrnd((&r3.x)[j]), bfrnd((&r2.x)[j]), 0x07060302u);
    short* row = vsm + (eq * 4 + j) * 66 + sq * 4;  // e-row, s = sq*4..+3
    *(unsigned*)(row)     = lo;
    *(unsigned*)(row + 2) = hh;
  }
  __syncthreads();
  // write out: thread -> e-row = tid>>2, 32B s-chunk = (tid&3)*16 shorts
  const int e = tid >> 2, sc = (tid & 3) * 16;
  const short* rr = vsm + e * 66 + sc;
  uint4 a, c;
  a.x = *(const unsigned*)(rr + 0);  a.y = *(const unsigned*)(rr + 2);
  a.z = *(const unsigned*)(rr + 4);  a.w = *(const unsigned*)(rr + 6);
  c.x = *(const unsigned*)(rr + 8);  c.y = *(const unsigned*)(rr + 10);
  c.z = *(const unsigned*)(rr + 12); c.w = *(const unsigned*)(rr + 14);
  short* vo = Vtg + ((size_t)bh * Ee + e) * Ss + s0 + sc;
  *(uint4*)(vo)     = a;
  *(uint4*)(vo + 8) = c;
}

// ---------- Main: flash attention, 32x32 MFMA, S^T orientation, BK=32 ----------
// 4 waves x 32 l-rows = 128 rows/block, grid 1024 (4 blocks/CU).
// Round-4 changes vs the 150us round-2 kernel:
//  * TRIPLE-buffered K/V + raw s_barrier with counted s_waitcnt vmcnt(2):
//    tile t's GLLs are issued 2 iterations ahead and only the 2 newest loads
//    may be outstanding at the barrier (wait-before-barrier = cross-wave safe).
//    No per-iteration vmcnt(0) drain.
//  * XCD-aware block swizzle: 16 same-bh blocks land on one XCD -> K/V staging
//    hits that XCD's L2.
//  * s_setprio(1) around MFMA clusters (T5).
// LDS (bytes): K 3x4096 [0,12288)  V^T 3x4096 [12288,24576)  kn2 [24576,32768)
constexpr int KB0 = 0, VB0 = 12288, KN2 = 24576;

__global__ __launch_bounds__(256, 4) void geom_attn_kernel(
    const float* __restrict__ Qg, const short* __restrict__ Kbf,
    const short* __restrict__ Vtg, const float* __restrict__ kn2g,
    float* __restrict__ outg, float* __restrict__ sumg) {
  __shared__ __align__(16) char smem[32768];

  const int tid = threadIdx.x, w = tid >> 6, lane = tid & 63;
  const int l31 = lane & 31, hi = lane >> 5;
  // XCD swizzle: physical bid -> work id so that XCD x (bid%8==x under
  // round-robin dispatch) gets 128 consecutive works = 8 full bh-groups.
  const int bid = blockIdx.x;
  const int wk = ((bid & 7) << 7) | (bid >> 3);
  const int lt = wk & 15, h = (wk >> 4) & 15, b = wk >> 8;
  const int bh = b * 16 + h;
  const int l0w = lt * 128 + w * 32;

  // Q B-frags (col = l31, k-slice = ks*16 + hi*8 + 0..7), pre-scaled by S2E
  short8 qB[4];
  float qn2v;
  {
    const float* qrow = Qg + (((size_t)b * Ll + l0w + l31) * Hh + h) * Ee;
    float qn = 0.f;
#pragma unroll
    for (int ks = 0; ks < 4; ++ks) {
      float4 a0 = mul4(*(const float4*)(qrow + ks * 16 + hi * 8), S2E);
      float4 a1 = mul4(*(const float4*)(qrow + ks * 16 + hi * 8 + 4), S2E);
      qn += sq4(a0) + sq4(a1);
      qB[ks] = pack8(a0, a1);
    }
    qn += __shfl_xor(qn, 32);  // other hi half holds the other 32 elems
    qn2v = qn;
  }

  // staging source pointers (XOR-swizzled 16B granules)
  const int rK = tid >> 3, pK = tid & 7;
  const char* kSrc = (const char*)Kbf + (size_t)bh * (Ss * 128) + rK * 128 + ((pK ^ (rK & 7)) * 16);
  const int eV = tid >> 2;
  const char* vSrc = (const char*)Vtg + (size_t)bh * (Ss * 128) + eV * (Ss * 2) + (((tid & 3) ^ (eV & 3)) * 16);
  char* kDstW = smem + KB0 + w * 1024;  // + buf*4096
  char* vDstW = smem + VB0 + w * 1024;

  // kn2 -> LDS once (8 KB; issued FIRST so the first vmcnt(2) covers it)
  {
    const char* knSrc = (const char*)kn2g + (size_t)bh * 8192 + (size_t)tid * 16;
    GLL(knSrc, smem + KN2 + w * 1024);
    GLL(knSrc + 4096, smem + KN2 + w * 1024 + 4096);
  }

  // prologue: stage tile 0 -> buf 0, tile 1 -> buf 1
  GLL(kSrc, kDstW);
  GLL(vSrc, vDstW);
  kSrc += 4096; vSrc += 64;
  GLL(kSrc, kDstW + 4096);
  GLL(vSrc, vDstW + 4096);
  kSrc += 4096; vSrc += 64;

  floatx16 o[2] = {};
  float lp = 0.f, scsum = 0.f;

  const int kSwz = l31 & 7;  // K tile: row s31=l31, granule (2ks+hi)^kSwz
  const int vSwz = l31 & 3;  // V tile: row et*32+e31, granule (2ks2+hi)^vSwz

  int pb = 0;  // buffer of tile `it` (= it % 3, maintained by rotation)
  for (int it = 0; it < 64; ++it) {
    // tile `it` was issued 2 iterations ago; only tile it+1's K,V (newest 2)
    // may remain outstanding. wait-BEFORE-barrier => after the barrier every
    // wave's tile-it granules are in LDS.
    if (it == 63) asm volatile("s_waitcnt vmcnt(0)" ::: "memory");
    else          asm volatile("s_waitcnt vmcnt(2)" ::: "memory");
    __builtin_amdgcn_s_barrier();
    asm volatile("" ::: "memory");  // no LDS access hoists above the barrier

    if (it < 62) {  // prefetch tile it+2 into buf (it+2)%3 (= previous buf)
      const int pf = pb ? pb - 1 : 2;
      GLL(kSrc, kDstW + pf * 4096);
      GLL(vSrc, vDstW + pf * 4096);
      kSrc += 4096; vSrc += 64;
    }

    const char* Kb = smem + KB0 + pb * 4096;
    const char* Vb = smem + VB0 + pb * 4096;

    // ---- K.Q^T -> S^T tile (32s x 32l); lane: col l=l31, rows s=(r&3)+8*(r>>2)+4*hi
    short8 ka0 = *(const short8*)(Kb + l31 * 128 + (((0 + hi) ^ kSwz) * 16));
    short8 ka1 = *(const short8*)(Kb + l31 * 128 + (((2 + hi) ^ kSwz) * 16));
    short8 ka2 = *(const short8*)(Kb + l31 * 128 + (((4 + hi) ^ kSwz) * 16));
    short8 ka3 = *(const short8*)(Kb + l31 * 128 + (((6 + hi) ^ kSwz) * 16));
    __builtin_amdgcn_s_setprio(1);
    floatx16 d = {};
    d = MFMA32(ka0, qB[0], d, 0, 0, 0);
    d = MFMA32(ka1, qB[1], d, 0, 0, 0);
    d = MFMA32(ka2, qB[2], d, 0, 0, 0);
    d = MFMA32(ka3, qB[3], d, 0, 0, 0);
    __builtin_amdgcn_s_setprio(0);

    // V B-frags (issue early; needed only at PV)
    short8 vb00 = *(const short8*)(Vb + l31 * 64 + (((0 + hi) ^ vSwz) * 16));
    short8 vb01 = *(const short8*)(Vb + l31 * 64 + (((2 + hi) ^ vSwz) * 16));
    short8 vb10 = *(const short8*)(Vb + (32 + l31) * 64 + (((0 + hi) ^ vSwz) * 16));
    short8 vb11 = *(const short8*)(Vb + (32 + l31) * 64 + (((2 + hi) ^ vSwz) * 16));

    // kn2 broadcast reads: knv[q] covers s = it*32 + 8q + 4hi + 0..3
    float4 knv0 = *(const float4*)(smem + KN2 + it * 128 + 0 * 32 + hi * 16);
    float4 knv1 = *(const float4*)(smem + KN2 + it * 128 + 1 * 32 + hi * 16);
    float4 knv2 = *(const float4*)(smem + KN2 + it * 128 + 2 * 32 + hi * 16);
    float4 knv3 = *(const float4*)(smem + KN2 + it * 128 + 3 * 32 + hi * 16);

    // ---- wedge scores + exp; pack to bf16 dword pairs
    unsigned pk[4][2];
#pragma unroll
    for (int q = 0; q < 4; ++q) {
      const float4 knq = (q == 0) ? knv0 : (q == 1) ? knv1 : (q == 2) ? knv2 : knv3;
      float pe[4], rt4[4];
#pragma unroll
      for (int r = 0; r < 4; ++r) {
        float dot = d[4 * q + r];
        float w2 = fmaf(-dot, dot, qn2v * (&knq.x)[r]);
        w2 = fmaxf(w2, EPS2);
        rt4[r] = __builtin_amdgcn_sqrtf(w2);      // = score*log2(e)
        pe[r]  = __builtin_amdgcn_exp2f(rt4[r]);  // exp(score), no max-sub
      }
      // tree-reduce the per-q partials (shorter dependency chains)
      scsum += (rt4[0] + rt4[1]) + (rt4[2] + rt4[3]);
      lp    += (pe[0] + pe[1]) + (pe[2] + pe[3]);
      pk[q][0] = __builtin_amdgcn_perm(__builtin_bit_cast(unsigned, pe[1]),
                                       __builtin_bit_cast(unsigned, pe[0]), 0x07060302u);
      pk[q][1] = __builtin_amdgcn_perm(__builtin_bit_cast(unsigned, pe[3]),
                                       __builtin_bit_cast(unsigned, pe[2]), 0x07060302u);
    }

    // ---- in-register P redistribution (4 permlane32_swap) ----
    pl32swap(pk[0][0], pk[1][0]);
    pl32swap(pk[0][1], pk[1][1]);
    pl32swap(pk[2][0], pk[3][0]);
    pl32swap(pk[2][1], pk[3][1]);
    union { unsigned u[4]; short8 s; } pa0, pa1;
    pa0.u[0] = pk[0][0]; pa0.u[1] = pk[0][1]; pa0.u[2] = pk[1][0]; pa0.u[3] = pk[1][1];
    pa1.u[0] = pk[2][0]; pa1.u[1] = pk[2][1]; pa1.u[2] = pk[3][0]; pa1.u[3] = pk[3][1];

    // ---- P.V (O[32l x 64e], 2 e-tiles x 2 k-steps)
    __builtin_amdgcn_s_setprio(1);
    o[0] = MFMA32(pa0.s, vb00, o[0], 0, 0, 0);
    o[0] = MFMA32(pa1.s, vb01, o[0], 0, 0, 0);
    o[1] = MFMA32(pa0.s, vb10, o[1], 0, 0, 0);
    o[1] = MFMA32(pa1.s, vb11, o[1], 0, 0, 0);
    __builtin_amdgcn_s_setprio(0);

    pb = (pb == 2) ? 0 : pb + 1;
  }

  __syncthreads();  // full drain before epilogue (cheap, once)

  // softmax denominator: fold the 2 hi replicas; lanes 0..31 hold lp[l31]
  lp += __shfl_xor(lp, 32);
  float lpinv = 1.0f / lp;

  // epilogue: lane (e31=l31, hi) holds O[row][et*32+e31], row=(r&3)+8*(r>>2)+4*hi
#pragma unroll
  for (int r = 0; r < 16; ++r) {
    const int row = (r & 3) + 8 * (r >> 2) + 4 * hi;
    float inv = __shfl(lpinv, row);
    float* orow = outg + (((size_t)b * Ll + l0w + row) * Hh + h) * Ee + l31;
    orow[0]  = o[0][r] * inv;
    orow[32] = o[1][r] * inv;
  }

  // mean|scores|: wave-reduce, one atomic per wave
  scsum += __shfl_xor(scsum, 1);
  scsum += __shfl_xor(scsum, 2);
  scsum += __shfl_xor(scsum, 4);
  scsum += __shfl_xor(scsum, 8);
  scsum += __shfl_xor(scsum, 16);
  scsum += __shfl_xor(scsum, 32);
  if (lane == 0) atomicAdd(sumg, scsum * SUM_SCALE);
}

extern "C" void kernel_launch(void* const* d_in, const int* in_sizes, int n_in,
                              void* d_out, int out_size, void* d_ws, size_t ws_size,
                              hipStream_t stream) {
  const float* Q = (const float*)d_in[0];
  const float* K = (const float*)d_in[1];
  const float* V = (const float*)d_in[2];
  float* out   = (float*)d_out;
  float* sumsc = out + (size_t)Bb * Ll * Hh * Ee;

  // workspace: Kbf 16.78 MB | Vt 16.78 MB | kn2 0.52 MB (ws >= 34.1 MB)
  short* Kbf = (short*)d_ws;
  short* Vtg = Kbf + (size_t)Bb * Hh * Ss * Ee;
  float* kn2 = (float*)(Vtg + (size_t)Bb * Hh * Ee * Ss);

  hipLaunchKernelGGL(geom_pre_kernel, dim3(Bb * Hh * (Ss / 64)), dim3(256), 0,
                     stream, K, V, Kbf, Vtg, kn2, sumsc);
  hipLaunchKernelGGL(geom_attn_kernel, dim3(Bb * Hh * (Ll / 128)), dim3(256), 0,
                     stream, Q, Kbf, Vtg, kn2, out, sumsc);
}